// Round 16
// baseline (156.199 us; speedup 1.0000x reference)
//
#include <hip/hip_runtime.h>
#include <hip/hip_bf16.h>
#include <math.h>

#define NV     32768
#define HIDDEN 768
#define SCALE  0.17677669529663687f

typedef __attribute__((ext_vector_type(8))) short short8;
typedef __attribute__((ext_vector_type(4))) float floatx4;
typedef __attribute__((ext_vector_type(8))) _Float16 h8;
typedef __attribute__((ext_vector_type(2))) _Float16 h2;
typedef __hip_bfloat16 bf16;

__device__ __forceinline__ void gload16(const void* g, void* l) {
    __builtin_amdgcn_global_load_lds(
        (const __attribute__((address_space(1))) unsigned int*)g,
        (__attribute__((address_space(3))) unsigned int*)l, 16, 0, 0);
}

__device__ __forceinline__ short f2bfs(float f) {
    bf16 b = __float2bfloat16(f);
    return *reinterpret_cast<short*>(&b);
}

// ---------------------------------------------------------------------------
// All weight converts in one kernel.
__global__ __launch_bounds__(256) void prep_kernel(
        const float* __restrict__ qkv_w, const float* __restrict__ proj_w,
        const float* __restrict__ w1, const float* __restrict__ w2,
        bf16* __restrict__ wqkv, bf16* __restrict__ wproj,
        bf16* __restrict__ w1t, bf16* __restrict__ w2t) {
    int i = blockIdx.x * 256 + threadIdx.x;
    if (i < 110592) {
        wqkv[i] = (bf16)qkv_w[i];
    } else if (i < 147456) {
        int j = i - 110592; int r = j / 192, c = j - r * 192;
        wproj[c * 192 + r] = (bf16)proj_w[j];
    } else if (i < 294912) {
        int j = i - 147456; int r = j / 768, c = j - r * 768;
        w1t[c * 192 + r] = (bf16)w1[j];
    } else if (i < 442368) {
        int j = i - 294912; int r = j / 192, c = j - r * 192;
        w2t[c * 768 + r] = (bf16)w2[j];
    }
}

// ---------------------------------------------------------------------------
// Fused transpose-in + LN1: x[C,H,W,D] f32 -> h[v][192] bf16 (raw) + lnb bf16.
__global__ __launch_bounds__(256) void tin_ln_kernel(
        const float* __restrict__ xin, const float* __restrict__ g,
        const float* __restrict__ be, bf16* __restrict__ h,
        bf16* __restrict__ lnb) {
    __shared__ float lds[32 * 193];
    int yx = blockIdx.x;
    int y = yx >> 5, x = yx & 31;
    for (int idx = threadIdx.x; idx < 192 * 32; idx += 256) {
        int c = idx >> 5, z = idx & 31;
        lds[z * 193 + c] = xin[(((size_t)c * 32 + y) * 32 + x) * 32 + z];
    }
    __syncthreads();
    int wave = threadIdx.x >> 6, lane = threadIdx.x & 63;
    float ga = g[lane], gb = g[lane + 64], gc = g[lane + 128];
    float ba = be[lane], bb = be[lane + 64], bc = be[lane + 128];
    for (int z = wave; z < 32; z += 4) {
        float x0 = lds[z * 193 + lane];
        float x1 = lds[z * 193 + lane + 64];
        float x2 = lds[z * 193 + lane + 128];
        float s = x0 + x1 + x2;
        #pragma unroll
        for (int m = 32; m; m >>= 1) s += __shfl_xor(s, m);
        float mu = s * (1.f / 192.f);
        float d0 = x0 - mu, d1 = x1 - mu, d2 = x2 - mu;
        float s2 = d0 * d0 + d1 * d1 + d2 * d2;
        #pragma unroll
        for (int m = 32; m; m >>= 1) s2 += __shfl_xor(s2, m);
        float rstd = rsqrtf(s2 * (1.f / 192.f) + 1e-5f);
        size_t v = (size_t)((z << 10) + (y << 5) + x) * 192;
        h[v + lane]         = (bf16)x0;
        h[v + lane + 64]    = (bf16)x1;
        h[v + lane + 128]   = (bf16)x2;
        lnb[v + lane]       = (bf16)(d0 * rstd * ga + ba);
        lnb[v + lane + 64]  = (bf16)(d1 * rstd * gb + bb);
        lnb[v + lane + 128] = (bf16)(d2 * rstd * gc + bc);
    }
}

// Transpose out: h[v][C] bf16 -> out[C,H,W,D] f32
__global__ __launch_bounds__(256) void tout_kernel(const bf16* __restrict__ h,
                                                   float* __restrict__ outp) {
    __shared__ float lds[32 * 193];
    int yx = blockIdx.x;
    int y = yx >> 5, x = yx & 31;
    for (int idx = threadIdx.x; idx < 32 * 192; idx += 256) {
        int z = idx / 192, c = idx - z * 192;
        lds[z * 193 + c] = __bfloat162float(h[((size_t)((z * 32 + y) * 32 + x)) * 192 + c]);
    }
    __syncthreads();
    for (int idx = threadIdx.x; idx < 192 * 32; idx += 256) {
        int c = idx >> 5, z = idx & 31;
        outp[(((size_t)c * 32 + y) * 32 + x) * 32 + z] = lds[z * 193 + c];
    }
}

// ---------------------------------------------------------------------------
// bf16 MFMA GEMM with FULL-K LDS residency: BK=192 (the whole K for qkv/fc1).
// Tile 128x64, 4 waves. Dynamic LDS 72 KB: A 128x192 (48 KB, 3 chunk regions
// of 16 KB) + B 64x192 (24 KB, 3 x 8 KB). One vmcnt(0)+barrier per 192-chunk
// (qkv/fc1: ONE per block, was 6 drains). KSTEPS = K/192 (4 for fc2).
// 72 KB x 2 blocks/CU = 144 KB <= 160 KB -> occupancy unchanged vs round 12.
// MODE 1: +bias +res -> bf16. MODE 2: +bias GELU -> bf16.
// MODE 3: scatter to attn layout as FP16.
template <int MODE, int KSTEPS>
__global__ __launch_bounds__(256, 2) void mgemm_kernel(
        const bf16* __restrict__ A,
        const bf16* __restrict__ Bw,
        void* __restrict__ Cp,
        const float* __restrict__ bias,
        const bf16* __restrict__ res,
        int M, int N) {
    extern __shared__ short smem[];
    short* Asm = smem;            // 3 x 16384 B chunk regions
    short* Bsm = smem + 24576;    // 3 x  8192 B chunk regions
    const int K = KSTEPS * 192;
    const int tid = threadIdx.x;
    const int lane = tid & 63;
    const int wave = tid >> 6;
    const int wm = wave >> 1, wn = wave & 1;
    const int m0 = blockIdx.x * 128;
    const int n0 = blockIdx.y * 64;

    const int srow = lane >> 3;
    const int scol = ((lane & 7) ^ ((lane >> 3) & 7)) * 16;

    floatx4 acc[4][2] = {};

    for (int kt = 0; kt < KSTEPS; ++kt) {
        const int k0 = kt * 192;
        // stage A: 48 segs (16/chunk), 12 per wave
        #pragma unroll
        for (int c = 0; c < 3; ++c) {
            #pragma unroll
            for (int s = 0; s < 4; ++s) {
                int q = wave * 4 + s;
                const char* g = (const char*)(A + (size_t)(m0 + q * 8 + srow) * K
                                              + k0 + c * 64) + scol;
                gload16(g, (char*)Asm + c * 16384 + q * 1024);
            }
        }
        // stage B: 24 segs (8/chunk), 6 per wave
        #pragma unroll
        for (int c = 0; c < 3; ++c) {
            #pragma unroll
            for (int s = 0; s < 2; ++s) {
                int q = wave * 2 + s;
                const char* g = (const char*)(Bw + (size_t)(n0 + q * 8 + srow) * K
                                              + k0 + c * 64) + scol;
                gload16(g, (char*)Bsm + c * 8192 + q * 1024);
            }
        }
        __syncthreads();          // the ONLY drain for this 192-chunk

        #pragma unroll
        for (int c = 0; c < 3; ++c) {
            #pragma unroll
            for (int ks = 0; ks < 2; ++ks) {
                short8 af[4], bfr[2];
                const int cb = ks * 64 + (lane >> 4) * 16;
                #pragma unroll
                for (int i = 0; i < 4; ++i) {
                    int row = wm * 64 + i * 16 + (lane & 15);
                    af[i] = *reinterpret_cast<const short8*>(
                        (const char*)Asm + c * 16384 + row * 128 + (cb ^ ((row & 7) << 4)));
                }
                #pragma unroll
                for (int j = 0; j < 2; ++j) {
                    int row = wn * 32 + j * 16 + (lane & 15);
                    bfr[j] = *reinterpret_cast<const short8*>(
                        (const char*)Bsm + c * 8192 + row * 128 + (cb ^ ((row & 7) << 4)));
                }
                #pragma unroll
                for (int i = 0; i < 4; ++i)
                    #pragma unroll
                    for (int j = 0; j < 2; ++j)
                        acc[i][j] = __builtin_amdgcn_mfma_f32_16x16x32_bf16(
                            af[i], bfr[j], acc[i][j], 0, 0, 0);
            }
        }
        if (KSTEPS > 1 && kt + 1 < KSTEPS) __syncthreads();  // protect restage
    }

    const int r4 = (lane >> 4) * 4;
    const int cc = lane & 15;
    #pragma unroll
    for (int i = 0; i < 4; ++i) {
        #pragma unroll
        for (int j = 0; j < 2; ++j) {
            int colg = n0 + wn * 32 + j * 16 + cc;
            float bv = (MODE == 1 || MODE == 2) ? bias[colg] : 0.f;
            #pragma unroll
            for (int rg = 0; rg < 4; ++rg) {
                int rowg = m0 + wm * 64 + i * 16 + r4 + rg;
                float v = acc[i][j][rg];
                if (MODE == 1 || MODE == 2) v += bv;
                if (MODE == 2) v = 0.5f * v * (1.f + erff(v * 0.70710678118654752f));
                if (MODE == 1) {
                    v += __bfloat162float(res[(size_t)rowg * N + colg]);
                    ((bf16*)Cp)[(size_t)rowg * N + colg] = (bf16)v;
                } else if (MODE == 2) {
                    ((bf16*)Cp)[(size_t)rowg * N + colg] = (bf16)v;
                } else {  // MODE 3: part/di/h scatter, FP16 output
                    int part = colg / 192;
                    int rem  = colg - part * 192;
                    int di   = rem >> 6, hc = rem & 63;
                    size_t addr = (size_t)part * (6 * (size_t)NV * 32)
                                + (size_t)((di << 1) + (hc >> 5)) * ((size_t)NV * 32)
                                + (size_t)rowg * 32 + (hc & 31);
                    ((_Float16*)Cp)[addr] = (_Float16)v;
                }
            }
        }
    }
}

// ---------------------------------------------------------------------------
// Fused proj GEMM + residual + LN2 (unchanged, full-row 64x192 tile).
__global__ __launch_bounds__(256) void projln_kernel(
        const bf16* __restrict__ A, const bf16* __restrict__ Bw,
        bf16* __restrict__ hres, bf16* __restrict__ lnout,
        const float* __restrict__ bias,
        const float* __restrict__ g2, const float* __restrict__ be2) {
    __shared__ short Asm[64 * 64];
    __shared__ short Bsm[192 * 64];
    const int tid = threadIdx.x;
    const int lane = tid & 63;
    const int wave = tid >> 6;
    const int m0 = blockIdx.x * 64;

    const int srow = lane >> 3;
    const int scol = ((lane & 7) ^ ((lane >> 3) & 7)) * 16;

    floatx4 acc[12] = {};

    for (int k0 = 0; k0 < 192; k0 += 64) {
        #pragma unroll
        for (int s = 0; s < 2; ++s) {
            int seg = wave * 2 + s;
            const char* g = (const char*)(A + (size_t)(m0 + seg * 8 + srow) * 192 + k0) + scol;
            gload16(g, (char*)Asm + seg * 1024);
        }
        #pragma unroll
        for (int s = 0; s < 6; ++s) {
            int seg = wave * 6 + s;
            const char* g = (const char*)(Bw + (size_t)(seg * 8 + srow) * 192 + k0) + scol;
            gload16(g, (char*)Bsm + seg * 1024);
        }
        __syncthreads();
        #pragma unroll
        for (int ks = 0; ks < 2; ++ks) {
            const int cb = ks * 64 + (lane >> 4) * 16;
            int arow = wave * 16 + (lane & 15);
            short8 af = *reinterpret_cast<const short8*>(
                (const char*)Asm + arow * 128 + (cb ^ ((arow & 7) << 4)));
            #pragma unroll
            for (int j = 0; j < 12; ++j) {
                int brow = j * 16 + (lane & 15);
                short8 bfr = *reinterpret_cast<const short8*>(
                    (const char*)Bsm + brow * 128 + (cb ^ ((brow & 7) << 4)));
                acc[j] = __builtin_amdgcn_mfma_f32_16x16x32_bf16(af, bfr, acc[j], 0, 0, 0);
            }
        }
        __syncthreads();
    }

    const int cc = lane & 15;
    #pragma unroll
    for (int rg = 0; rg < 4; ++rg) {
        int rowg = m0 + wave * 16 + (lane >> 4) * 4 + rg;
        float vals[12];
        float vsum = 0.f;
        #pragma unroll
        for (int j = 0; j < 12; ++j) {
            int col = j * 16 + cc;
            float v = acc[j][rg] + bias[col]
                    + __bfloat162float(hres[(size_t)rowg * 192 + col]);
            vals[j] = v;
            vsum += v;
        }
        #pragma unroll
        for (int m = 8; m; m >>= 1) vsum += __shfl_xor(vsum, m);
        float mu = vsum * (1.f / 192.f);
        float vsq = 0.f;
        #pragma unroll
        for (int j = 0; j < 12; ++j) {
            float d = vals[j] - mu;
            vsq += d * d;
        }
        #pragma unroll
        for (int m = 8; m; m >>= 1) vsq += __shfl_xor(vsq, m);
        float rstd = rsqrtf(vsq * (1.f / 192.f) + 1e-5f);
        #pragma unroll
        for (int j = 0; j < 12; ++j) {
            int col = j * 16 + cc;
            hres[(size_t)rowg * 192 + col] = (bf16)vals[j];
            lnout[(size_t)rowg * 192 + col] =
                (bf16)((vals[j] - mu) * rstd * g2[col] + be2[col]);
        }
    }
}

// ---------------------------------------------------------------------------
// Attention v6 (unchanged, passing): K staged in LDS (18 KB), V direct from
// L2, single-pass softmax, clamped-OOB staging, XCD-chunked swizzle.
__global__ __launch_bounds__(128) void attn_kernel(
        const _Float16* __restrict__ qa,
        const _Float16* __restrict__ ka,
        const _Float16* __restrict__ va,
        bf16* __restrict__ attn_out) {
    __shared__ _Float16 lds[9216];                  // 18 KB: 9 K rows
    const int lin = blockIdx.x;                     // 0..6143
    const int swz = (lin & 7) * 768 + (lin >> 3);   // XCD-contiguous chunks
    const int dh  = swz >> 10;                      // 0..5
    const int yz  = swz & 1023;
    const int di = dh >> 1;
    const int r  = di + 1;
    const int z = yz >> 5, y = yz & 31;
    const int t = threadIdx.x;

    const _Float16* kb = ka + (size_t)dh * NV * 32;
    const _Float16* vb = va + (size_t)dh * NV * 32;

    #pragma unroll
    for (int s = 0; s < 9; ++s) {
        const int dz = s / 3 - 1, dy = s % 3 - 1;
        int zz = z + dz * r, yy = y + dy * r;
        zz = zz < 0 ? 0 : (zz > 31 ? 31 : zz);
        yy = yy < 0 ? 0 : (yy > 31 ? 31 : yy);
        const _Float16* src = kb + (size_t)(((zz << 10) + (yy << 5)) * 32);
        gload16((const char*)src + t * 16,
                (char*)lds + s * 2048 + (t >> 6) * 1024);
    }

    const int x = t >> 2, c4 = t & 3;
    const int v = (z << 10) + (y << 5) + x;
    h8 q8 = *reinterpret_cast<const h8*>(qa + ((size_t)dh * NV + v) * 32 + c4 * 8);
    h2 q01 = {q8[0], q8[1]}, q23 = {q8[2], q8[3]};
    h2 q45 = {q8[4], q8[5]}, q67 = {q8[6], q8[7]};

    __syncthreads();

    float denom = 0.f;
    h2 o01 = {0, 0}, o23 = {0, 0}, o45 = {0, 0}, o67 = {0, 0};
    const float cexp = SCALE * 1.44269504088896f;

    #pragma unroll
    for (int kk = 0; kk < 27; ++kk) {
        const int dz = kk / 9 - 1, dy = (kk / 3) % 3 - 1, dx = kk % 3 - 1;
        const int slot = (dz + 1) * 3 + (dy + 1);
        int nz = z + dz * r, ny = y + dy * r, nx = x + dx * r;
        bool ok = ((unsigned)nz < 32u) & ((unsigned)ny < 32u) & ((unsigned)nx < 32u);
        int rx = ok ? nx : x;
        int nvv = ok ? v + r * ((dz << 10) + (dy << 5) + dx) : v;
        h8 k8 = *reinterpret_cast<const h8*>(
            (const char*)lds + slot * 2048 + rx * 64 + c4 * 16);
        h8 v8 = *reinterpret_cast<const h8*>(vb + (size_t)nvv * 32 + c4 * 8);
        h2 a = q01 * (h2){k8[0], k8[1]};
        a = q23 * (h2){k8[2], k8[3]} + a;
        a = q45 * (h2){k8[4], k8[5]} + a;
        a = q67 * (h2){k8[6], k8[7]} + a;
        float d = (float)a[0] + (float)a[1];
        d += __shfl_xor(d, 1);
        d += __shfl_xor(d, 2);
        float p = exp2f(ok ? d * cexp : 0.f);
        denom += p;
        float w = ok ? p : 0.f;
        _Float16 wh = (_Float16)w;
        h2 w2 = {wh, wh};
        o01 = w2 * (h2){v8[0], v8[1]} + o01;
        o23 = w2 * (h2){v8[2], v8[3]} + o23;
        o45 = w2 * (h2){v8[4], v8[5]} + o45;
        o67 = w2 * (h2){v8[6], v8[7]} + o67;
    }
    float inv = 1.f / denom;

    bf16* op = attn_out + (size_t)v * 192 + di * 64 + (dh & 1) * 32 + c4 * 8;
    short8 st;
    st[0] = f2bfs((float)o01[0] * inv); st[1] = f2bfs((float)o01[1] * inv);
    st[2] = f2bfs((float)o23[0] * inv); st[3] = f2bfs((float)o23[1] * inv);
    st[4] = f2bfs((float)o45[0] * inv); st[5] = f2bfs((float)o45[1] * inv);
    st[6] = f2bfs((float)o67[0] * inv); st[7] = f2bfs((float)o67[1] * inv);
    *reinterpret_cast<short8*>(op) = st;
}

// ---------------------------------------------------------------------------
extern "C" void kernel_launch(void* const* d_in, const int* in_sizes, int n_in,
                              void* d_out, int out_size, void* d_ws, size_t ws_size,
                              hipStream_t stream) {
    const float* x      = (const float*)d_in[0];
    const float* qkv_w  = (const float*)d_in[1];
    const float* proj_w = (const float*)d_in[2];
    const float* proj_b = (const float*)d_in[3];
    const float* g1     = (const float*)d_in[4];
    const float* be1    = (const float*)d_in[5];
    const float* g2     = (const float*)d_in[6];
    const float* be2    = (const float*)d_in[7];
    const float* w1     = (const float*)d_in[8];
    const float* b1     = (const float*)d_in[9];
    const float* w2     = (const float*)d_in[10];
    const float* b2     = (const float*)d_in[11];
    float* out = (float*)d_out;

    char* p = (char*)d_ws;
    bf16* h     = (bf16*)p;  p += (size_t)NV * 192 * 2;
    bf16* lnb   = (bf16*)p;  p += (size_t)NV * 192 * 2;
    bf16* qkvb  = (bf16*)p;  p += (size_t)NV * 576 * 2;
    bf16* attnb = (bf16*)p;  p += (size_t)NV * 192 * 2;
    bf16* tb    = qkvb;  // [NV][768] overlaps dead qkvb+attnb exactly
    bf16* wqkv  = (bf16*)p;  p += (size_t)576 * 192 * 2;
    bf16* wproj = (bf16*)p;  p += (size_t)192 * 192 * 2;
    bf16* w1t   = (bf16*)p;  p += (size_t)768 * 192 * 2;
    bf16* w2t   = (bf16*)p;  p += (size_t)192 * 768 * 2;

    _Float16* qa = (_Float16*)qkvb;
    _Float16* ka = qa + (size_t)6 * NV * 32;
    _Float16* va = qa + (size_t)12 * NV * 32;

    const size_t GEMM_LDS = 73728;   // 48 KB A + 24 KB B

    prep_kernel<<<(442368 + 255) / 256, 256, 0, stream>>>(
        qkv_w, proj_w, w1, w2, wqkv, wproj, w1t, w2t);
    tin_ln_kernel<<<1024, 256, 0, stream>>>(x, g1, be1, h, lnb);

    // QKV: K=192 fully LDS-resident (KSTEPS=1)
    mgemm_kernel<3, 1><<<dim3(NV / 128, 576 / 64), 256, GEMM_LDS, stream>>>(
        lnb, wqkv, qkvb, nullptr, nullptr, NV, 576);
    attn_kernel<<<6144, 128, 0, stream>>>(qa, ka, va, attnb);
    projln_kernel<<<NV / 64, 256, 0, stream>>>(
        attnb, wproj, h, lnb, proj_b, g2, be2);

    // fc1: K=192 (KSTEPS=1)
    mgemm_kernel<2, 1><<<dim3(NV / 128, HIDDEN / 64), 256, GEMM_LDS, stream>>>(
        lnb, w1t, tb, b1, nullptr, NV, HIDDEN);
    // fc2: K=768 (KSTEPS=4)
    mgemm_kernel<1, 4><<<dim3(NV / 128, 192 / 64), 256, GEMM_LDS, stream>>>(
        tb, w2t, h, b2, h, NV, 192);

    tout_kernel<<<1024, 256, 0, stream>>>(h, out);
}

// Round 17
// 131.326 us; speedup vs baseline: 1.1894x; 1.1894x over previous
//
#include <hip/hip_runtime.h>
#include <hip/hip_bf16.h>
#include <math.h>

#define NV     32768
#define HIDDEN 768
#define SCALE  0.17677669529663687f

typedef __attribute__((ext_vector_type(8))) short short8;
typedef __attribute__((ext_vector_type(4))) float floatx4;
typedef __attribute__((ext_vector_type(8))) _Float16 h8;
typedef __attribute__((ext_vector_type(2))) _Float16 h2;
typedef __hip_bfloat16 bf16;

__device__ __forceinline__ void gload16(const void* g, void* l) {
    __builtin_amdgcn_global_load_lds(
        (const __attribute__((address_space(1))) unsigned int*)g,
        (__attribute__((address_space(3))) unsigned int*)l, 16, 0, 0);
}

__device__ __forceinline__ short f2bfs(float f) {
    bf16 b = __float2bfloat16(f);
    return *reinterpret_cast<short*>(&b);
}

// ---------------------------------------------------------------------------
// Merged prep + transpose-in + LN1.
// Blocks 0..1023: x[C,H,W,D] f32 -> h[v][192] bf16 + lnb bf16 (one yx column).
// Blocks 1024..2751: weight converts (1728 blocks x 256 = 442368 elements).
__global__ __launch_bounds__(256) void prep_tin_ln_kernel(
        const float* __restrict__ xin, const float* __restrict__ g,
        const float* __restrict__ be, bf16* __restrict__ h,
        bf16* __restrict__ lnb,
        const float* __restrict__ qkv_w, const float* __restrict__ proj_w,
        const float* __restrict__ w1, const float* __restrict__ w2,
        bf16* __restrict__ wqkv, bf16* __restrict__ wproj,
        bf16* __restrict__ w1t, bf16* __restrict__ w2t) {
    if (blockIdx.x >= 1024) {
        int i = (blockIdx.x - 1024) * 256 + threadIdx.x;
        if (i < 110592) {
            wqkv[i] = (bf16)qkv_w[i];
        } else if (i < 147456) {
            int j = i - 110592; int r = j / 192, c = j - r * 192;
            wproj[c * 192 + r] = (bf16)proj_w[j];
        } else if (i < 294912) {
            int j = i - 147456; int r = j / 768, c = j - r * 768;
            w1t[c * 192 + r] = (bf16)w1[j];
        } else if (i < 442368) {
            int j = i - 294912; int r = j / 192, c = j - r * 192;
            w2t[c * 768 + r] = (bf16)w2[j];
        }
        return;
    }
    __shared__ float lds[32 * 193];
    int yx = blockIdx.x;
    int y = yx >> 5, x = yx & 31;
    for (int idx = threadIdx.x; idx < 192 * 32; idx += 256) {
        int c = idx >> 5, z = idx & 31;
        lds[z * 193 + c] = xin[(((size_t)c * 32 + y) * 32 + x) * 32 + z];
    }
    __syncthreads();
    int wave = threadIdx.x >> 6, lane = threadIdx.x & 63;
    float ga = g[lane], gb = g[lane + 64], gc = g[lane + 128];
    float ba = be[lane], bb = be[lane + 64], bc = be[lane + 128];
    for (int z = wave; z < 32; z += 4) {
        float x0 = lds[z * 193 + lane];
        float x1 = lds[z * 193 + lane + 64];
        float x2 = lds[z * 193 + lane + 128];
        float s = x0 + x1 + x2;
        #pragma unroll
        for (int m = 32; m; m >>= 1) s += __shfl_xor(s, m);
        float mu = s * (1.f / 192.f);
        float d0 = x0 - mu, d1 = x1 - mu, d2 = x2 - mu;
        float s2 = d0 * d0 + d1 * d1 + d2 * d2;
        #pragma unroll
        for (int m = 32; m; m >>= 1) s2 += __shfl_xor(s2, m);
        float rstd = rsqrtf(s2 * (1.f / 192.f) + 1e-5f);
        size_t v = (size_t)((z << 10) + (y << 5) + x) * 192;
        h[v + lane]         = (bf16)x0;
        h[v + lane + 64]    = (bf16)x1;
        h[v + lane + 128]   = (bf16)x2;
        lnb[v + lane]       = (bf16)(d0 * rstd * ga + ba);
        lnb[v + lane + 64]  = (bf16)(d1 * rstd * gb + bb);
        lnb[v + lane + 128] = (bf16)(d2 * rstd * gc + bc);
    }
}

// Transpose out: h[v][C] bf16 -> out[C,H,W,D] f32
__global__ __launch_bounds__(256) void tout_kernel(const bf16* __restrict__ h,
                                                   float* __restrict__ outp) {
    __shared__ float lds[32 * 193];
    int yx = blockIdx.x;
    int y = yx >> 5, x = yx & 31;
    for (int idx = threadIdx.x; idx < 32 * 192; idx += 256) {
        int z = idx / 192, c = idx - z * 192;
        lds[z * 193 + c] = __bfloat162float(h[((size_t)((z * 32 + y) * 32 + x)) * 192 + c]);
    }
    __syncthreads();
    for (int idx = threadIdx.x; idx < 192 * 32; idx += 256) {
        int c = idx >> 5, z = idx & 31;
        outp[(((size_t)c * 32 + y) * 32 + x) * 32 + z] = lds[z * 193 + c];
    }
}

// ---------------------------------------------------------------------------
// bf16 MFMA GEMM (round-12 optimum: 128x64 tile, BK=64, 4 waves, (256,2)).
// MODE 1: +bias +res -> bf16. MODE 2: +bias GELU -> bf16.
// MODE 3: scatter to attn layout as FP16.
template <int MODE>
__global__ __launch_bounds__(256, 2) void mgemm_kernel(
        const bf16* __restrict__ A,
        const bf16* __restrict__ Bw,
        void* __restrict__ Cp,
        const float* __restrict__ bias,
        const bf16* __restrict__ res,
        int M, int N, int K) {
    __shared__ short Asm[128 * 64];
    __shared__ short Bsm[64 * 64];
    const int tid = threadIdx.x;
    const int lane = tid & 63;
    const int wave = tid >> 6;
    const int wm = wave >> 1, wn = wave & 1;
    const int m0 = blockIdx.x * 128;
    const int n0 = blockIdx.y * 64;

    const int srow = lane >> 3;
    const int scol = ((lane & 7) ^ ((lane >> 3) & 7)) * 16;

    floatx4 acc[4][2] = {};

    for (int k0 = 0; k0 < K; k0 += 64) {
        #pragma unroll
        for (int s = 0; s < 4; ++s) {
            int seg = wave * 4 + s;
            const char* g = (const char*)(A + (size_t)(m0 + seg * 8 + srow) * K + k0) + scol;
            gload16(g, (char*)Asm + seg * 1024);
        }
        #pragma unroll
        for (int s = 0; s < 2; ++s) {
            int seg = wave * 2 + s;
            const char* g = (const char*)(Bw + (size_t)(n0 + seg * 8 + srow) * K + k0) + scol;
            gload16(g, (char*)Bsm + seg * 1024);
        }
        __syncthreads();
        #pragma unroll
        for (int ks = 0; ks < 2; ++ks) {
            short8 af[4], bfr[2];
            const int cb = ks * 64 + (lane >> 4) * 16;
            #pragma unroll
            for (int i = 0; i < 4; ++i) {
                int row = wm * 64 + i * 16 + (lane & 15);
                af[i] = *reinterpret_cast<const short8*>(
                    (const char*)Asm + row * 128 + (cb ^ ((row & 7) << 4)));
            }
            #pragma unroll
            for (int j = 0; j < 2; ++j) {
                int row = wn * 32 + j * 16 + (lane & 15);
                bfr[j] = *reinterpret_cast<const short8*>(
                    (const char*)Bsm + row * 128 + (cb ^ ((row & 7) << 4)));
            }
            #pragma unroll
            for (int i = 0; i < 4; ++i)
                #pragma unroll
                for (int j = 0; j < 2; ++j)
                    acc[i][j] = __builtin_amdgcn_mfma_f32_16x16x32_bf16(
                        af[i], bfr[j], acc[i][j], 0, 0, 0);
        }
        __syncthreads();
    }

    const int r4 = (lane >> 4) * 4;
    const int cc = lane & 15;
    #pragma unroll
    for (int i = 0; i < 4; ++i) {
        #pragma unroll
        for (int j = 0; j < 2; ++j) {
            int colg = n0 + wn * 32 + j * 16 + cc;
            float bv = (MODE == 1 || MODE == 2) ? bias[colg] : 0.f;
            #pragma unroll
            for (int rg = 0; rg < 4; ++rg) {
                int rowg = m0 + wm * 64 + i * 16 + r4 + rg;
                float v = acc[i][j][rg];
                if (MODE == 1 || MODE == 2) v += bv;
                if (MODE == 2) v = 0.5f * v * (1.f + erff(v * 0.70710678118654752f));
                if (MODE == 1) {
                    v += __bfloat162float(res[(size_t)rowg * N + colg]);
                    ((bf16*)Cp)[(size_t)rowg * N + colg] = (bf16)v;
                } else if (MODE == 2) {
                    ((bf16*)Cp)[(size_t)rowg * N + colg] = (bf16)v;
                } else {  // MODE 3: part/di/h scatter, FP16 output
                    int part = colg / 192;
                    int rem  = colg - part * 192;
                    int di   = rem >> 6, hc = rem & 63;
                    size_t addr = (size_t)part * (6 * (size_t)NV * 32)
                                + (size_t)((di << 1) + (hc >> 5)) * ((size_t)NV * 32)
                                + (size_t)rowg * 32 + (hc & 31);
                    ((_Float16*)Cp)[addr] = (_Float16)v;
                }
            }
        }
    }
}

// ---------------------------------------------------------------------------
// Fused proj GEMM + residual + LN2 (full-row 64x192 tile).
__global__ __launch_bounds__(256) void projln_kernel(
        const bf16* __restrict__ A, const bf16* __restrict__ Bw,
        bf16* __restrict__ hres, bf16* __restrict__ lnout,
        const float* __restrict__ bias,
        const float* __restrict__ g2, const float* __restrict__ be2) {
    __shared__ short Asm[64 * 64];
    __shared__ short Bsm[192 * 64];
    const int tid = threadIdx.x;
    const int lane = tid & 63;
    const int wave = tid >> 6;
    const int m0 = blockIdx.x * 64;

    const int srow = lane >> 3;
    const int scol = ((lane & 7) ^ ((lane >> 3) & 7)) * 16;

    floatx4 acc[12] = {};

    for (int k0 = 0; k0 < 192; k0 += 64) {
        #pragma unroll
        for (int s = 0; s < 2; ++s) {
            int seg = wave * 2 + s;
            const char* g = (const char*)(A + (size_t)(m0 + seg * 8 + srow) * 192 + k0) + scol;
            gload16(g, (char*)Asm + seg * 1024);
        }
        #pragma unroll
        for (int s = 0; s < 6; ++s) {
            int seg = wave * 6 + s;
            const char* g = (const char*)(Bw + (size_t)(seg * 8 + srow) * 192 + k0) + scol;
            gload16(g, (char*)Bsm + seg * 1024);
        }
        __syncthreads();
        #pragma unroll
        for (int ks = 0; ks < 2; ++ks) {
            const int cb = ks * 64 + (lane >> 4) * 16;
            int arow = wave * 16 + (lane & 15);
            short8 af = *reinterpret_cast<const short8*>(
                (const char*)Asm + arow * 128 + (cb ^ ((arow & 7) << 4)));
            #pragma unroll
            for (int j = 0; j < 12; ++j) {
                int brow = j * 16 + (lane & 15);
                short8 bfr = *reinterpret_cast<const short8*>(
                    (const char*)Bsm + brow * 128 + (cb ^ ((brow & 7) << 4)));
                acc[j] = __builtin_amdgcn_mfma_f32_16x16x32_bf16(af, bfr, acc[j], 0, 0, 0);
            }
        }
        __syncthreads();
    }

    const int cc = lane & 15;
    #pragma unroll
    for (int rg = 0; rg < 4; ++rg) {
        int rowg = m0 + wave * 16 + (lane >> 4) * 4 + rg;
        float vals[12];
        float vsum = 0.f;
        #pragma unroll
        for (int j = 0; j < 12; ++j) {
            int col = j * 16 + cc;
            float v = acc[j][rg] + bias[col]
                    + __bfloat162float(hres[(size_t)rowg * 192 + col]);
            vals[j] = v;
            vsum += v;
        }
        #pragma unroll
        for (int m = 8; m; m >>= 1) vsum += __shfl_xor(vsum, m);
        float mu = vsum * (1.f / 192.f);
        float vsq = 0.f;
        #pragma unroll
        for (int j = 0; j < 12; ++j) {
            float d = vals[j] - mu;
            vsq += d * d;
        }
        #pragma unroll
        for (int m = 8; m; m >>= 1) vsq += __shfl_xor(vsq, m);
        float rstd = rsqrtf(vsq * (1.f / 192.f) + 1e-5f);
        #pragma unroll
        for (int j = 0; j < 12; ++j) {
            int col = j * 16 + cc;
            hres[(size_t)rowg * 192 + col] = (bf16)vals[j];
            lnout[(size_t)rowg * 192 + col] =
                (bf16)((vals[j] - mu) * rstd * g2[col] + be2[col]);
        }
    }
}

// ---------------------------------------------------------------------------
// Attention v6 (best-measured): K staged in LDS (18 KB), V direct from L2,
// single-pass softmax, clamped-OOB staging, XCD-chunked swizzle.
__global__ __launch_bounds__(128) void attn_kernel(
        const _Float16* __restrict__ qa,
        const _Float16* __restrict__ ka,
        const _Float16* __restrict__ va,
        bf16* __restrict__ attn_out) {
    __shared__ _Float16 lds[9216];                  // 18 KB: 9 K rows
    const int lin = blockIdx.x;                     // 0..6143
    const int swz = (lin & 7) * 768 + (lin >> 3);   // XCD-contiguous chunks
    const int dh  = swz >> 10;                      // 0..5
    const int yz  = swz & 1023;
    const int di = dh >> 1;
    const int r  = di + 1;
    const int z = yz >> 5, y = yz & 31;
    const int t = threadIdx.x;

    const _Float16* kb = ka + (size_t)dh * NV * 32;
    const _Float16* vb = va + (size_t)dh * NV * 32;

    #pragma unroll
    for (int s = 0; s < 9; ++s) {
        const int dz = s / 3 - 1, dy = s % 3 - 1;
        int zz = z + dz * r, yy = y + dy * r;
        zz = zz < 0 ? 0 : (zz > 31 ? 31 : zz);
        yy = yy < 0 ? 0 : (yy > 31 ? 31 : yy);
        const _Float16* src = kb + (size_t)(((zz << 10) + (yy << 5)) * 32);
        gload16((const char*)src + t * 16,
                (char*)lds + s * 2048 + (t >> 6) * 1024);
    }

    const int x = t >> 2, c4 = t & 3;
    const int v = (z << 10) + (y << 5) + x;
    h8 q8 = *reinterpret_cast<const h8*>(qa + ((size_t)dh * NV + v) * 32 + c4 * 8);
    h2 q01 = {q8[0], q8[1]}, q23 = {q8[2], q8[3]};
    h2 q45 = {q8[4], q8[5]}, q67 = {q8[6], q8[7]};

    __syncthreads();

    float denom = 0.f;
    h2 o01 = {0, 0}, o23 = {0, 0}, o45 = {0, 0}, o67 = {0, 0};
    const float cexp = SCALE * 1.44269504088896f;

    #pragma unroll
    for (int kk = 0; kk < 27; ++kk) {
        const int dz = kk / 9 - 1, dy = (kk / 3) % 3 - 1, dx = kk % 3 - 1;
        const int slot = (dz + 1) * 3 + (dy + 1);
        int nz = z + dz * r, ny = y + dy * r, nx = x + dx * r;
        bool ok = ((unsigned)nz < 32u) & ((unsigned)ny < 32u) & ((unsigned)nx < 32u);
        int rx = ok ? nx : x;
        int nvv = ok ? v + r * ((dz << 10) + (dy << 5) + dx) : v;
        h8 k8 = *reinterpret_cast<const h8*>(
            (const char*)lds + slot * 2048 + rx * 64 + c4 * 16);
        h8 v8 = *reinterpret_cast<const h8*>(vb + (size_t)nvv * 32 + c4 * 8);
        h2 a = q01 * (h2){k8[0], k8[1]};
        a = q23 * (h2){k8[2], k8[3]} + a;
        a = q45 * (h2){k8[4], k8[5]} + a;
        a = q67 * (h2){k8[6], k8[7]} + a;
        float d = (float)a[0] + (float)a[1];
        d += __shfl_xor(d, 1);
        d += __shfl_xor(d, 2);
        float p = exp2f(ok ? d * cexp : 0.f);
        denom += p;
        float w = ok ? p : 0.f;
        _Float16 wh = (_Float16)w;
        h2 w2 = {wh, wh};
        o01 = w2 * (h2){v8[0], v8[1]} + o01;
        o23 = w2 * (h2){v8[2], v8[3]} + o23;
        o45 = w2 * (h2){v8[4], v8[5]} + o45;
        o67 = w2 * (h2){v8[6], v8[7]} + o67;
    }
    float inv = 1.f / denom;

    bf16* op = attn_out + (size_t)v * 192 + di * 64 + (dh & 1) * 32 + c4 * 8;
    short8 st;
    st[0] = f2bfs((float)o01[0] * inv); st[1] = f2bfs((float)o01[1] * inv);
    st[2] = f2bfs((float)o23[0] * inv); st[3] = f2bfs((float)o23[1] * inv);
    st[4] = f2bfs((float)o45[0] * inv); st[5] = f2bfs((float)o45[1] * inv);
    st[6] = f2bfs((float)o67[0] * inv); st[7] = f2bfs((float)o67[1] * inv);
    *reinterpret_cast<short8*>(op) = st;
}

// ---------------------------------------------------------------------------
extern "C" void kernel_launch(void* const* d_in, const int* in_sizes, int n_in,
                              void* d_out, int out_size, void* d_ws, size_t ws_size,
                              hipStream_t stream) {
    const float* x      = (const float*)d_in[0];
    const float* qkv_w  = (const float*)d_in[1];
    const float* proj_w = (const float*)d_in[2];
    const float* proj_b = (const float*)d_in[3];
    const float* g1     = (const float*)d_in[4];
    const float* be1    = (const float*)d_in[5];
    const float* g2     = (const float*)d_in[6];
    const float* be2    = (const float*)d_in[7];
    const float* w1     = (const float*)d_in[8];
    const float* b1     = (const float*)d_in[9];
    const float* w2     = (const float*)d_in[10];
    const float* b2     = (const float*)d_in[11];
    float* out = (float*)d_out;

    char* p = (char*)d_ws;
    bf16* h     = (bf16*)p;  p += (size_t)NV * 192 * 2;
    bf16* lnb   = (bf16*)p;  p += (size_t)NV * 192 * 2;
    bf16* qkvb  = (bf16*)p;  p += (size_t)NV * 576 * 2;
    bf16* attnb = (bf16*)p;  p += (size_t)NV * 192 * 2;
    bf16* tb    = qkvb;  // [NV][768] overlaps dead qkvb+attnb exactly
    bf16* wqkv  = (bf16*)p;  p += (size_t)576 * 192 * 2;
    bf16* wproj = (bf16*)p;  p += (size_t)192 * 192 * 2;
    bf16* w1t   = (bf16*)p;  p += (size_t)768 * 192 * 2;
    bf16* w2t   = (bf16*)p;  p += (size_t)192 * 768 * 2;

    _Float16* qa = (_Float16*)qkvb;
    _Float16* ka = qa + (size_t)6 * NV * 32;
    _Float16* va = qa + (size_t)12 * NV * 32;

    // merged weight-prep + transpose-in + LN1 (1024 tin blocks + 1728 prep)
    prep_tin_ln_kernel<<<2752, 256, 0, stream>>>(
        x, g1, be1, h, lnb,
        qkv_w, proj_w, w1, w2, wqkv, wproj, w1t, w2t);

    mgemm_kernel<3><<<dim3(NV / 128, 576 / 64), 256, 0, stream>>>(
        lnb, wqkv, qkvb, nullptr, nullptr, NV, 576, 192);
    attn_kernel<<<6144, 128, 0, stream>>>(qa, ka, va, attnb);
    projln_kernel<<<NV / 64, 256, 0, stream>>>(
        attnb, wproj, h, lnb, proj_b, g2, be2);

    mgemm_kernel<2><<<dim3(NV / 128, HIDDEN / 64), 256, 0, stream>>>(
        lnb, w1t, tb, b1, nullptr, NV, HIDDEN, 192);
    mgemm_kernel<1><<<dim3(NV / 128, 192 / 64), 256, 0, stream>>>(
        tb, w2t, h, b2, h, NV, 192, HIDDEN);

    tout_kernel<<<1024, 256, 0, stream>>>(h, out);
}